// Round 1
// 482.603 us; speedup vs baseline: 1.1846x; 1.1846x over previous
//
#include <hip/hip_runtime.h>

#define HO 62
#define WO 62
#define CIN 32
#define COUT 64
#define BATCH 16
#define KROW 288                // CIN*9 floats per (position, o) weight row
#define JT 2                    // j positions per block (31 tiles exactly -> no clamps)
#define COLS 4                  // JT + 2 window columns
#define ROWS 128                // JT*COUT weight rows staged per block (contiguous in HBM)
#define PHASE_C 4               // channels per pipeline phase
#define PHASE_F (PHASE_C * 9)   // 36 floats per row per phase
#define RSTRIDE 37              // LDS row stride (37%32=5, odd -> conflict-free o-row reads)
#define NPHASE (CIN / PHASE_C)  // 8

__global__ __launch_bounds__(256, 2)
void lc2d_kernel(const float* __restrict__ x,
                 const float* __restrict__ wgt,
                 float* __restrict__ out) {
    // x window for 2 adjacent output columns: [c][kh][col][batch]  (24576 B)
    __shared__ __align__(16) float win[CIN][3][COLS][BATCH];
    // double-buffered weight slab: 128 rows x 36 floats (+1 pad) per phase (37888 B)
    __shared__ __align__(16) float wlds[2][ROWS * RSTRIDE];

    const int blk = blockIdx.x;
    const int i  = blk % HO;                 // consecutive blocks share x rows (L2 locality)
    const int j0 = (blk / HO) * JT;          // 0,2,...,60
    const int t  = threadIdx.x;

    // ---- per-thread staging geometry (invariant across phases) ----
    // phase region = [128 rows][18 float2]; 2304 float2 / 256 thr = 9 each.
    // consecutive lanes -> consecutive addresses (coalesced runs of 144 B per row).
    int goffq[9], loffq[9];
    #pragma unroll
    for (int q = 0; q < 9; q++) {
        const int f2  = q * 256 + t;
        const int row = f2 / 18;
        const int pos = f2 - row * 18;
        goffq[q] = row * KROW + pos * 2;      // global float offset (+= phase*36)
        loffq[q] = row * RSTRIDE + pos * 2;   // LDS float offset
    }

    // block's weight slab is contiguous: positions j0, j0+1 are adjacent 72 KB
    const float* wbase = wgt + (size_t)(i * WO + j0) * (COUT * KROW);

    // ---- issue phase-0 weight loads first (latency hides under x staging) ----
    float2 stg[9];
    #pragma unroll
    for (int q = 0; q < 9; q++)
        stg[q] = *(const float2*)(wbase + goffq[q]);

    // ---- stage x window: float2 along j per (b,c,kh) row ----
    for (int r = t; r < BATCH * CIN * 3 * 2; r += 256) {   // 12 iters
        const int half = r & 1;
        const int row  = r >> 1;              // b*96 + c*3 + kh
        const int kh   = row % 3;
        const int bc   = row / 3;
        const int c    = bc & 31;
        const int b    = bc >> 5;
        const float2 v = *(const float2*)(x + (((b * CIN + c) * 64) + (i + kh)) * 64
                                            + j0 + half * 2);
        win[c][kh][half * 2][b]     = v.x;
        win[c][kh][half * 2 + 1][b] = v.y;
    }

    // ---- write phase-0 weights to LDS ----
    #pragma unroll
    for (int q = 0; q < 9; q++) {
        wlds[0][loffq[q]]     = stg[q].x;
        wlds[0][loffq[q] + 1] = stg[q].y;
    }
    __syncthreads();

    const int wsel = t >> 6;     // wave = batch quad (b = wsel*4 + bb)
    const int o    = t & 63;     // lane = output channel

    float acc[JT][4];
    #pragma unroll
    for (int jj = 0; jj < JT; jj++)
        #pragma unroll
        for (int bb = 0; bb < 4; bb++) acc[jj][bb] = 0.0f;

    const float* xbase = &win[0][0][0][wsel * 4];   // wave-uniform -> broadcast reads
    const int wr0 = o * RSTRIDE;

    for (int p = 0; p < NPHASE; p++) {
        const int cur = p & 1;

        // issue next-phase global loads BEFORE compute (async-split; vmcnt waits
        // land just before the LDS writes after ~4 c-iters of FMAs)
        if (p < NPHASE - 1) {
            const float* wp = wbase + (p + 1) * PHASE_F;
            #pragma unroll
            for (int q = 0; q < 9; q++)
                stg[q] = *(const float2*)(wp + goffq[q]);
        }

        const float* wb = &wlds[cur][wr0];
        #pragma unroll
        for (int cc = 0; cc < PHASE_C; cc++) {
            const int c = p * PHASE_C + cc;
            // 9 weights per j-position from LDS (odd stride -> 2 lanes/bank, free)
            float wq[JT][9];
            #pragma unroll
            for (int jj = 0; jj < JT; jj++) {
                const float* wr = wb + jj * (64 * RSTRIDE) + cc * 9;
                #pragma unroll
                for (int q = 0; q < 9; q++) wq[jj][q] = wr[q];
            }
            #pragma unroll
            for (int kh = 0; kh < 3; kh++) {
                float4 xv[COLS];
                const float* xb = xbase + (c * 3 + kh) * (COLS * BATCH);
                #pragma unroll
                for (int cl = 0; cl < COLS; cl++)
                    xv[cl] = *(const float4*)(xb + cl * BATCH);   // 16B broadcast
                #pragma unroll
                for (int jj = 0; jj < JT; jj++) {
                    #pragma unroll
                    for (int kw = 0; kw < 3; kw++) {
                        const float w  = wq[jj][kh * 3 + kw];
                        const float4 xx = xv[jj + kw];
                        acc[jj][0] += w * xx.x;
                        acc[jj][1] += w * xx.y;
                        acc[jj][2] += w * xx.z;
                        acc[jj][3] += w * xx.w;
                    }
                }
            }
        }

        // write next phase into the other buffer; readers of it finished at the
        // previous barrier, so one barrier per phase suffices
        if (p < NPHASE - 1) {
            #pragma unroll
            for (int q = 0; q < 9; q++) {
                wlds[cur ^ 1][loffq[q]]     = stg[q].x;
                wlds[cur ^ 1][loffq[q] + 1] = stg[q].y;
            }
        }
        __syncthreads();
    }

    // ---- epilogue: sigmoid + float2 stores along j (j0 even -> 8B aligned) ----
    #pragma unroll
    for (int bb = 0; bb < 4; bb++) {
        const int b = wsel * 4 + bb;
        float* op = out + (((size_t)(b * COUT + o) * HO + i) * WO + j0);
        float2 s;
        s.x = 1.0f / (1.0f + __expf(-acc[0][bb]));
        s.y = 1.0f / (1.0f + __expf(-acc[1][bb]));
        *(float2*)op = s;
    }
}

extern "C" void kernel_launch(void* const* d_in, const int* in_sizes, int n_in,
                              void* d_out, int out_size, void* d_ws, size_t ws_size,
                              hipStream_t stream) {
    const float* x   = (const float*)d_in[0];
    const float* wgt = (const float*)d_in[1];
    float* out       = (float*)d_out;
    const int grid = HO * (WO / JT);   // 62 * 31 = 1922 blocks
    lc2d_kernel<<<dim3(grid), dim3(256), 0, stream>>>(x, wgt, out);
}

// Round 2
// 481.975 us; speedup vs baseline: 1.1862x; 1.0013x over previous
//
#include <hip/hip_runtime.h>
#include <stdint.h>

#define HO 62
#define WO 62
#define CIN 32
#define COUT 64
#define BATCH 16
#define KROW 288              // CIN*9 floats per (position, o) weight row
#define JT 2                  // j positions per block (31 tiles exactly)
#define NJT (WO / JT)         // 31
#define ROWS 128              // JT*COUT weight rows per block slab (contiguous in HBM)
#define PC 2                  // channels per phase
#define NPH (CIN / PC)        // 16
#define PH_DW (PC * 9)        // 18 real dwords per row per phase
#define RSTRIDE 32            // padded dwords per LDS row (pow2 -> XOR swizzle works)
#define SLOTS (ROWS * RSTRIDE)// 4096 dwords per buffer
#define NXCD 8

typedef const __attribute__((address_space(1))) void* gptr_t;
typedef __attribute__((address_space(3))) void* lptr_t;

__global__ __launch_bounds__(256, 4)
void lc2d_kernel(const float* __restrict__ x,
                 const float* __restrict__ wgt,
                 float* __restrict__ out) {
    // double-buffered weight slab: [row 128][32 dwords], XOR-swizzled (32 KiB)
    __shared__ __align__(16) float wlds[2][SLOTS];

    // ---- bijective XCD chunk swizzle (nwg=1922, q=240, r=2; m204 formula) ----
    // j-tile fastest within a chunk: sequential weight streaming, same-i x reuse,
    // and the 8 j-tiles of one 64B output line stay on one XCD -> L2 write merge.
    const int orig = blockIdx.x;
    const int nwg  = HO * NJT;
    const int qch  = nwg / NXCD, rch = nwg % NXCD;
    const int xcd  = orig % NXCD, pos = orig / NXCD;
    const int wg   = ((xcd < rch) ? xcd * (qch + 1)
                                  : rch * (qch + 1) + (xcd - rch) * qch) + pos;
    const int i  = wg / NJT;
    const int j0 = (wg % NJT) * JT;

    const int t    = threadIdx.x;
    const int wsel = t >> 6;                       // wave = batch quad
    const int o    = t & 63;                       // lane = output channel
    const int ws_u = __builtin_amdgcn_readfirstlane(wsel);

    const float* wbase = wgt + (size_t)(i * WO + j0) * (COUT * KROW);

    // ---- per-lane staging source offsets (dwords), inverse of the LDS swizzle ----
    // LDS slot s: row=s>>5, k=s&31; logical dword l = k ^ ((row&7)<<2);
    // logical layout per row-phase: [cc 2][12] (9 data + 3 pad). Pads load dup data
    // (same cache lines, never read back).
    int goff[16];
    #pragma unroll
    for (int g = 0; g < 16; g++) {
        const int s   = wsel * 1024 + g * 64 + o;
        const int row = s >> 5;
        const int k   = s & 31;
        const int l   = k ^ ((row & 7) << 2);
        int src;
        if (l < 24) {
            const int cc = l / 12;
            int r2 = l % 12; if (r2 > 8) r2 = 8;
            src = row * KROW + cc * 9 + r2;
        } else {
            src = row * KROW;                      // pad slot
        }
        goff[g] = src;
    }

    // ---- prologue: stage phase 0 into buffer 0 (direct global->LDS DMA) ----
    #pragma unroll
    for (int g = 0; g < 16; g++)
        __builtin_amdgcn_global_load_lds((gptr_t)(wbase + goff[g]),
                                         (lptr_t)&wlds[0][ws_u * 1024 + g * 64],
                                         4, 0, 0);

    float acc[JT][4];
    #pragma unroll
    for (int jj = 0; jj < JT; jj++)
        #pragma unroll
        for (int bb = 0; bb < 4; bb++) acc[jj][bb] = 0.0f;

    // x row base per batch element of this wave's quad (x stays in L1/L2; no LDS)
    const float* xp[4];
    #pragma unroll
    for (int bb = 0; bb < 4; bb++)
        xp[bb] = x + ((size_t)(wsel * 4 + bb) * CIN) * 4096 + i * 64 + j0;

    const int swz = (o & 7) << 2;                  // read-side XOR (dword units)

    __syncthreads();                               // drains the prologue DMA

    int cur = 0;
    for (int p = 0; p < NPH; p++) {
        // issue next-phase DMA before compute; the phase barrier drains it
        if (p + 1 < NPH) {
            const float* wsrc = wbase + (p + 1) * PH_DW;
            #pragma unroll
            for (int g = 0; g < 16; g++)
                __builtin_amdgcn_global_load_lds((gptr_t)(wsrc + goff[g]),
                                                 (lptr_t)&wlds[cur ^ 1][ws_u * 1024 + g * 64],
                                                 4, 0, 0);
        }

        #pragma unroll
        for (int cc = 0; cc < PC; cc++) {
            const int c = p * PC + cc;

            // 9 weights per jj: 2x ds_read_b128 + 1x ds_read_b32, conflict-free via swizzle
            float4 wA[JT], wB[JT]; float w8[JT];
            #pragma unroll
            for (int jj = 0; jj < JT; jj++) {
                const int base = (jj * 64 + o) * RSTRIDE + cc * 12;
                wA[jj] = *(const float4*)&wlds[cur][(base + 0) ^ swz];
                wB[jj] = *(const float4*)&wlds[cur][(base + 4) ^ swz];
                w8[jj] = wlds[cur][(base + 8) ^ swz];
            }

            #pragma unroll
            for (int kh = 0; kh < 3; kh++) {
                // 4 cols x 4 batch: wave-uniform float2 global loads (8B aligned, L1-hot)
                float2 xa[4], xb[4];
                #pragma unroll
                for (int bb = 0; bb < 4; bb++) {
                    const float* xr = xp[bb] + (c * 64 + kh) * 64;
                    xa[bb] = *(const float2*)xr;
                    xb[bb] = *(const float2*)(xr + 2);
                }
                #pragma unroll
                for (int jj = 0; jj < JT; jj++) {
                    #pragma unroll
                    for (int kw = 0; kw < 3; kw++) {
                        const int q = kh * 3 + kw;
                        const float w = (q < 4) ? ((const float*)&wA[jj])[q]
                                      : (q < 8) ? ((const float*)&wB[jj])[q - 4]
                                                : w8[jj];
                        const int col = jj + kw;   // 0..3
                        #pragma unroll
                        for (int bb = 0; bb < 4; bb++) {
                            const float xv = (col == 0) ? xa[bb].x
                                           : (col == 1) ? xa[bb].y
                                           : (col == 2) ? xb[bb].x
                                                        : xb[bb].y;
                            acc[jj][bb] += w * xv;
                        }
                    }
                }
            }
        }
        __syncthreads();                           // buffer swap point
        cur ^= 1;
    }

    // ---- epilogue: sigmoid + float2 stores along j (j0 even -> 8B aligned) ----
    #pragma unroll
    for (int bb = 0; bb < 4; bb++) {
        const int b = wsel * 4 + bb;
        float* op = out + (((size_t)(b * COUT + o) * HO + i) * WO + j0);
        float2 s;
        s.x = 1.0f / (1.0f + __expf(-acc[0][bb]));
        s.y = 1.0f / (1.0f + __expf(-acc[1][bb]));
        *(float2*)op = s;
    }
}

extern "C" void kernel_launch(void* const* d_in, const int* in_sizes, int n_in,
                              void* d_out, int out_size, void* d_ws, size_t ws_size,
                              hipStream_t stream) {
    const float* x   = (const float*)d_in[0];
    const float* wgt = (const float*)d_in[1];
    float* out       = (float*)d_out;
    const int grid = HO * NJT;   // 1922 blocks
    lc2d_kernel<<<dim3(grid), dim3(256), 0, stream>>>(x, wgt, out);
}